// Round 4
// baseline (3119.063 us; speedup 1.0000x reference)
//
#include <hip/hip_runtime.h>
#include <stdint.h>
#include <cstdio>

typedef unsigned short u16;
typedef __attribute__((ext_vector_type(8))) __bf16 bf16x8;
typedef __attribute__((ext_vector_type(4))) float f32x4;
typedef __attribute__((ext_vector_type(4))) int i32x4;

#define AGENT __HIP_MEMORY_SCOPE_AGENT

__device__ __forceinline__ float bf2f(u16 u) {
  unsigned int x = ((unsigned int)u) << 16;
  return __builtin_bit_cast(float, x);
}
__device__ __forceinline__ u16 f2bf(float f) {
  unsigned int x = __builtin_bit_cast(unsigned int, f);
  unsigned int r = (x + 0x7fffu + ((x >> 16) & 1u)) >> 16;
  return (u16)r;
}
__device__ __forceinline__ float sigm(float x) { return 1.f / (1.f + __expf(-x)); }
__device__ __forceinline__ float tanh_f(float x) { return 1.f - 2.f / (__expf(2.f * x) + 1.f); }

__device__ __forceinline__ int2 pack2(i32x4 v) {
  int2 o;
  o.x = (int)(((unsigned)v[0] >> 16) | ((unsigned)v[1] & 0xffff0000u));
  o.y = (int)(((unsigned)v[2] >> 16) | ((unsigned)v[3] & 0xffff0000u));
  return o;
}

// ---------- fp32 -> bf16 convert (x) ----------
__global__ __launch_bounds__(256) void k_cvt(const float* __restrict__ in, u16* __restrict__ out, int n4) {
  int i = blockIdx.x * 256 + threadIdx.x;
  if (i >= n4) return;
  float4 f = ((const float4*)in)[i];
  ushort4 o;
  o.x = f2bf(f.x); o.y = f2bf(f.y); o.z = f2bf(f.z); o.w = f2bf(f.w);
  ((ushort4*)out)[i] = o;
}

// ---------- pack Wx0 [768][3072] -> B-fragment order [nt=192][kt=24][lane=64][j=8] ----------
__global__ __launch_bounds__(256) void k_pack_wx(const float* __restrict__ Wx, u16* __restrict__ Bp) {
  int idx = blockIdx.x * 256 + threadIdx.x;
  if (idx >= 2359296) return;
  int j = idx & 7;
  int l = (idx >> 3) & 63;
  int t = idx >> 9;          // nt*24 + kt
  int kt = t % 24, nt = t / 24;
  int k = kt * 32 + (l >> 4) * 8 + j;
  int n = nt * 16 + (l & 15);
  Bp[idx] = f2bf(Wx[(size_t)k * 3072 + n]);
}

// ---------- pack Wh0 -> per-member slices [w=32][nt=6][kt=24][lane=64][j=8] ----------
__global__ __launch_bounds__(256) void k_pack_wh(const float* __restrict__ Wh, u16* __restrict__ Wp) {
  int idx = blockIdx.x * 256 + threadIdx.x;
  if (idx >= 2359296) return;
  int j = idx & 7;
  int l = (idx >> 3) & 63;
  int t = idx >> 9;          // w*144 + nt*24 + kt
  int kt = t % 24;
  int tmp = t / 24;          // w*6 + nt
  int nt = tmp % 6, w = tmp / 6;
  int k = kt * 32 + (l >> 4) * 8 + j;
  int c = nt * 16 + (l & 15);          // 0..95
  int q = c / 24, u = c - q * 24;
  int gcol = q * 768 + w * 24 + u;
  Wp[idx] = f2bf(Wh[(size_t)k * 3072 + gcol]);
}

// ---------- pack concat [Wx1; Wh1] (K=1536) -> [w=32][nt=6][kt=48][lane=64][j=8] ----------
__global__ __launch_bounds__(256) void k_pack_wc(const float* __restrict__ Wx, const float* __restrict__ Wh,
                                                 u16* __restrict__ Wp) {
  int idx = blockIdx.x * 256 + threadIdx.x;
  if (idx >= 4718592) return;
  int j = idx & 7;
  int l = (idx >> 3) & 63;
  int t = idx >> 9;          // w*288 + nt*48 + kt
  int kt = t % 48;
  int tmp = t / 48;          // w*6 + nt
  int nt = tmp % 6, w = tmp / 6;
  int k = kt * 32 + (l >> 4) * 8 + j;   // 0..1535 concat K
  int c = nt * 16 + (l & 15);
  int q = c / 24, u = c - q * 24;
  int gcol = q * 768 + w * 24 + u;
  float val = (k < 768) ? Wx[(size_t)k * 3072 + gcol] : Wh[(size_t)(k - 768) * 3072 + gcol];
  Wp[idx] = f2bf(val);
}

// ---------- GEMM: xg[16384][3072] bf16 = x_bf[16384][768] @ Wxp0 ----------
__global__ __launch_bounds__(256, 2) void k_gemm(const u16* __restrict__ A, const u16* __restrict__ Bp,
                                                 u16* __restrict__ C) {
  const int bid = blockIdx.x;
  const int bm = bid & 127, bn = bid >> 7;   // 128 x 24
  const int tid = threadIdx.x, lane = tid & 63, wv = tid >> 6;
  const int wm = wv >> 1, wn = wv & 1;
  const int row0 = bm * 128 + wm * 64;
  const int col0 = bn * 128 + wn * 64;
  const int rlo = lane & 15, rhi = lane >> 4;
  f32x4 acc[4][4] = {};
  const u16* Ab = A + (size_t)(row0 + rlo) * 768 + rhi * 8;
  const u16* Bb = Bp + ((size_t)(bn * 8 + wn * 4) * 24 * 64 + lane) * 8;
#pragma unroll 2
  for (int kt = 0; kt < 24; ++kt) {
    bf16x8 a[4], b[4];
#pragma unroll
    for (int i = 0; i < 4; ++i) a[i] = *(const bf16x8*)(Ab + (size_t)i * 16 * 768 + kt * 32);
#pragma unroll
    for (int j = 0; j < 4; ++j) b[j] = *(const bf16x8*)(Bb + (size_t)j * 24 * 64 * 8 + (size_t)kt * 64 * 8);
#pragma unroll
    for (int i = 0; i < 4; ++i)
#pragma unroll
      for (int j = 0; j < 4; ++j)
        acc[i][j] = __builtin_amdgcn_mfma_f32_16x16x32_bf16(a[i], b[j], acc[i][j], 0, 0, 0);
  }
#pragma unroll
  for (int i = 0; i < 4; ++i)
#pragma unroll
    for (int j = 0; j < 4; ++j)
#pragma unroll
      for (int r = 0; r < 4; ++r) {
        int row = row0 + i * 16 + rhi * 4 + r;
        int col = col0 + j * 16 + rlo;
        C[(size_t)row * 3072 + col] = f2bf(acc[i][j][r]);
      }
}

// ---------- fused 2-layer persistent LSTM recurrence, wavefront-pipelined ----------
// 256 WGs x 384 threads. wid<128: layer0 (g=wid>>5 in 0..3, w=wid&31); wid>=128: layer1.
// Groups own 8 seqs. Member w owns 24 hidden units (96 gate cols = 6 MFMA col-tiles, 1/wave).
// h_t published as tagged dwords (bf16<<16 | (t+1)) into ring-4 slot t&3 of h{0,1}buf.
// L0 step t: consume h0_{t-1}; throttle on h1_{t-4} (ring safety). L1 step t: consume h0_t + h1_{t-1};
// gates1 = [h0_t | h1_{t-1}] @ Wcp (K=1536) + b1  (input projection folded in; no GEMM for layer 1).
__global__ __launch_bounds__(384, 2) void k_rec2(
    const u16* __restrict__ xg,    // [16384][3072] bf16 (layer0 input proj)
    const u16* __restrict__ Whp0,  // [32][6][24][64][8]
    const u16* __restrict__ Wcp,   // [32][6][48][64][8]
    const float* __restrict__ b0,
    const float* __restrict__ b1,
    int* h0buf,                    // [4 groups][4 slots][6144] tagged dwords (zeroed)
    int* h1buf,                    // same
    float* __restrict__ out) {     // [32][512][768] fp32 (pre-LN)
  __shared__ __align__(16) u16 ldsW[36864];   // 72KB: L1's Wc frags kt 36..47, all 6 nt
  __shared__ __align__(16) int hlds[8 * 776]; // A rows; L0 stride 392, L1 stride 776
  __shared__ float glds[8][96];

  const int wid = blockIdx.x;
  const bool lay1 = wid >= 128;
  const int g = (wid & 127) >> 5, w = wid & 31;
  const int tid = threadIdx.x, lane = tid & 63, wv = tid >> 6;

  // ---- weight fragments -> registers (+ LDS tail for layer 1) ----
  bf16x8 fE[18], fO[18];
  if (!lay1) {
    const u16* bp = Whp0 + (((size_t)(w * 6 + wv) * 24) * 64 + lane) * 8;
#pragma unroll
    for (int kk = 0; kk < 12; ++kk) {
      fE[kk] = *(const bf16x8*)(bp + (size_t)(2 * kk) * 512);
      fO[kk] = *(const bf16x8*)(bp + (size_t)(2 * kk + 1) * 512);
    }
  } else {
    const u16* bp = Wcp + (((size_t)(w * 6 + wv) * 48) * 64 + lane) * 8;
#pragma unroll
    for (int kk = 0; kk < 18; ++kk) {
      fE[kk] = *(const bf16x8*)(bp + (size_t)(2 * kk) * 512);
      fO[kk] = *(const bf16x8*)(bp + (size_t)(2 * kk + 1) * 512);
    }
    // stage kt 36..47 x 6 nt into LDS (once)
    for (int i = tid; i < 4608; i += 384) {
      int nt = i / 768, rem = i % 768;
      int kt2 = rem >> 6, ch = rem & 63;
      ((int4*)ldsW)[i] = ((const int4*)Wcp)[((size_t)(w * 6 + nt) * 48 + 36 + kt2) * 64 + ch];
    }
  }

  const bool cellt = tid < 192;
  const int u = tid % 24, s = tid / 24;   // s in 0..7 for cell threads
  const int seq = g * 8 + (cellt ? s : 0);
  float bv0 = 0, bv1 = 0, bv2 = 0, bv3 = 0, xv0 = 0, xv1 = 0, xv2 = 0, xv3 = 0;
  int gc0 = 0, gc1 = 0, gc2 = 0, gc3 = 0;
  if (cellt) {
    int col = w * 24 + u;
    gc0 = col; gc1 = 768 + col; gc2 = 1536 + col; gc3 = 2304 + col;
    const float* bb = lay1 ? b1 : b0;
    bv0 = bb[gc0]; bv1 = bb[gc1]; bv2 = bb[gc2]; bv3 = bb[gc3];
    if (!lay1) {
      const u16* xr = xg + (size_t)seq * 512 * 3072;
      xv0 = bf2f(xr[gc0]); xv1 = bf2f(xr[gc1]); xv2 = bf2f(xr[gc2]); xv3 = bf2f(xr[gc3]);
    }
  }
  float cst = 0.f;
  const int slc = lane & 7;             // A-frag row (rows 8-15 wrap; results discarded)
  const int g4 = (lane >> 4) * 4;       // A-frag dword col base
  const int r = tid / 48, cb8 = (tid % 48) * 8;   // stage chunk -> hlds row/col
  int* pub = (lay1 ? h1buf : h0buf);
  int guard = 0;

  __syncthreads();

  for (int t = 0; t < 512; ++t) {
    // ================= poll + stage h into hlds =================
    if (!lay1) {
      // consume h0_{t-1} (slot (t-1)&3, tag t); throttle: h1_{t-4} published (slot t&3, tag >= t-3)
      const int* base = h0buf + ((size_t)(g * 4 + ((t - 1) & 3))) * 6144 + tid * 16;
      const int* pt = h1buf + ((size_t)(g * 4 + (t & 3))) * 6144 + (lane & 31) * 24;
      const int* p0 = base, *p1 = base + 4, *p2 = base + 8, *p3 = base + 12;
      const int e = t;
      const int te = t - 3;
      i32x4 v0, v1, v2, v3; int tv;
      bool ok;
      do {
        asm volatile(
            "global_load_dwordx4 %0, %5, off sc0 sc1\n\t"
            "global_load_dwordx4 %1, %6, off sc0 sc1\n\t"
            "global_load_dwordx4 %2, %7, off sc0 sc1\n\t"
            "global_load_dwordx4 %3, %8, off sc0 sc1\n\t"
            "global_load_dword %4, %9, off sc0 sc1\n\t"
            "s_waitcnt vmcnt(0)"
            : "=&v"(v0), "=&v"(v1), "=&v"(v2), "=&v"(v3), "=&v"(tv)
            : "v"(p0), "v"(p1), "v"(p2), "v"(p3), "v"(pt)
            : "memory");
        ok = true;
#pragma unroll
        for (int j = 0; j < 4; ++j)
          ok = ok && ((v0[j] & 0xffff) == e) && ((v1[j] & 0xffff) == e) &&
               ((v2[j] & 0xffff) == e) && ((v3[j] & 0xffff) == e);
        ok = ok && ((t < 4) || ((tv & 0xffff) >= te));
      } while (!ok && ++guard < (1 << 22));
      int4 o01; int2 a = pack2(v0), b = pack2(v1);
      o01.x = a.x; o01.y = a.y; o01.z = b.x; o01.w = b.y;
      int4 o23; a = pack2(v2); b = pack2(v3);
      o23.x = a.x; o23.y = a.y; o23.z = b.x; o23.w = b.y;
      *(int4*)&hlds[r * 392 + cb8] = o01;
      *(int4*)&hlds[r * 392 + cb8 + 4] = o23;
    } else {
      // consume h0_t (slot t&3, tag t+1) and h1_{t-1} (slot (t-1)&3, tag t)
      const int* ba = h0buf + ((size_t)(g * 4 + (t & 3))) * 6144 + tid * 16;
      const int* bb = h1buf + ((size_t)(g * 4 + ((t - 1) & 3))) * 6144 + tid * 16;
      const int e0 = t + 1, e1 = t;
      i32x4 a0_, a1_, a2_, a3_, c0_, c1_, c2_, c3_;
      bool ok;
      do {
        asm volatile(
            "global_load_dwordx4 %0, %8, off sc0 sc1\n\t"
            "global_load_dwordx4 %1, %9, off sc0 sc1\n\t"
            "global_load_dwordx4 %2, %10, off sc0 sc1\n\t"
            "global_load_dwordx4 %3, %11, off sc0 sc1\n\t"
            "global_load_dwordx4 %4, %12, off sc0 sc1\n\t"
            "global_load_dwordx4 %5, %13, off sc0 sc1\n\t"
            "global_load_dwordx4 %6, %14, off sc0 sc1\n\t"
            "global_load_dwordx4 %7, %15, off sc0 sc1\n\t"
            "s_waitcnt vmcnt(0)"
            : "=&v"(a0_), "=&v"(a1_), "=&v"(a2_), "=&v"(a3_),
              "=&v"(c0_), "=&v"(c1_), "=&v"(c2_), "=&v"(c3_)
            : "v"(ba), "v"(ba + 4), "v"(ba + 8), "v"(ba + 12),
              "v"(bb), "v"(bb + 4), "v"(bb + 8), "v"(bb + 12)
            : "memory");
        ok = true;
#pragma unroll
        for (int j = 0; j < 4; ++j) {
          ok = ok && ((a0_[j] & 0xffff) == e0) && ((a1_[j] & 0xffff) == e0) &&
               ((a2_[j] & 0xffff) == e0) && ((a3_[j] & 0xffff) == e0);
          ok = ok && ((c0_[j] & 0xffff) == e1) && ((c1_[j] & 0xffff) == e1) &&
               ((c2_[j] & 0xffff) == e1) && ((c3_[j] & 0xffff) == e1);
        }
      } while (!ok && ++guard < (1 << 22));
      int4 o; int2 x, y;
      x = pack2(a0_); y = pack2(a1_); o.x = x.x; o.y = x.y; o.z = y.x; o.w = y.y;
      *(int4*)&hlds[r * 776 + cb8] = o;
      x = pack2(a2_); y = pack2(a3_); o.x = x.x; o.y = x.y; o.z = y.x; o.w = y.y;
      *(int4*)&hlds[r * 776 + cb8 + 4] = o;
      x = pack2(c0_); y = pack2(c1_); o.x = x.x; o.y = x.y; o.z = y.x; o.w = y.y;
      *(int4*)&hlds[r * 776 + 384 + cb8] = o;
      x = pack2(c2_); y = pack2(c3_); o.x = x.x; o.y = x.y; o.z = y.x; o.w = y.y;
      *(int4*)&hlds[r * 776 + 384 + cb8 + 4] = o;
    }
    __syncthreads();  // B3: hlds ready

    // ================= MFMA: gates[8 seq][16 cols of tile wv] =================
    f32x4 acc0 = {0, 0, 0, 0}, acc1 = {0, 0, 0, 0};
    if (!lay1) {
      const int abase = slc * 392 + g4;
#pragma unroll
      for (int kk = 0; kk < 12; ++kk) {
        bf16x8 afe = *(const bf16x8*)&hlds[abase + (2 * kk) * 16];
        bf16x8 afo = *(const bf16x8*)&hlds[abase + (2 * kk + 1) * 16];
        acc0 = __builtin_amdgcn_mfma_f32_16x16x32_bf16(afe, fE[kk], acc0, 0, 0, 0);
        acc1 = __builtin_amdgcn_mfma_f32_16x16x32_bf16(afo, fO[kk], acc1, 0, 0, 0);
      }
    } else {
      const int abase = slc * 776 + g4;
#pragma unroll
      for (int kk = 0; kk < 18; ++kk) {
        bf16x8 afe = *(const bf16x8*)&hlds[abase + (2 * kk) * 16];
        bf16x8 afo = *(const bf16x8*)&hlds[abase + (2 * kk + 1) * 16];
        acc0 = __builtin_amdgcn_mfma_f32_16x16x32_bf16(afe, fE[kk], acc0, 0, 0, 0);
        acc1 = __builtin_amdgcn_mfma_f32_16x16x32_bf16(afo, fO[kk], acc1, 0, 0, 0);
      }
#pragma unroll
      for (int kk2 = 0; kk2 < 6; ++kk2) {
        int kt = 36 + 2 * kk2;
        bf16x8 afe = *(const bf16x8*)&hlds[abase + kt * 16];
        bf16x8 afo = *(const bf16x8*)&hlds[abase + (kt + 1) * 16];
        bf16x8 bE = *(const bf16x8*)(ldsW + ((size_t)(wv * 12 + 2 * kk2) * 64 + lane) * 8);
        bf16x8 bO = *(const bf16x8*)(ldsW + ((size_t)(wv * 12 + 2 * kk2 + 1) * 64 + lane) * 8);
        acc0 = __builtin_amdgcn_mfma_f32_16x16x32_bf16(afe, bE, acc0, 0, 0, 0);
        acc1 = __builtin_amdgcn_mfma_f32_16x16x32_bf16(afo, bO, acc1, 0, 0, 0);
      }
    }
    acc0 += acc1;
    // D: col = lane&15, row = (lane>>4)*4 + reg -> rows 0-7 live in lanes 0-31
    if (lane < 32) {
#pragma unroll
      for (int rr = 0; rr < 4; ++rr) glds[(lane >> 4) * 4 + rr][wv * 16 + (lane & 15)] = acc0[rr];
    }
    __syncthreads();  // B1: gates ready

    if (cellt) {
      float p0 = xv0 + glds[s][u] + bv0;
      float p1 = xv1 + glds[s][24 + u] + bv1;
      float p2 = xv2 + glds[s][48 + u] + bv2;
      float p3 = xv3 + glds[s][72 + u] + bv3;
      float ig = sigm(p0), fg = sigm(p1), gg = tanh_f(p2), og = sigm(p3);
      cst = fg * cst + ig * gg;
      float h = og * tanh_f(cst);
      // publish tagged h into ring slot t&3 (fire-and-forget)
      int* dst = pub + ((size_t)(g * 4 + (t & 3))) * 6144 + s * 768 + w * 24 + u;
      int val = (int)(((unsigned)f2bf(h) << 16) | (unsigned)(t + 1));
      __hip_atomic_store(dst, val, __ATOMIC_RELAXED, AGENT);
      if (lay1) {
        out[((size_t)seq * 512 + t) * 768 + w * 24 + u] = h;
      } else if (t + 1 < 512) {
        const u16* xr = xg + ((size_t)seq * 512 + t + 1) * 3072;
        xv0 = bf2f(xr[gc0]); xv1 = bf2f(xr[gc1]); xv2 = bf2f(xr[gc2]); xv3 = bf2f(xr[gc3]);
      }
    }
  }
}

// ---------- LayerNorm (in-place safe) ----------
__global__ __launch_bounds__(256) void k_ln(const float* __restrict__ in, const float* __restrict__ sc,
                                            const float* __restrict__ bi, float* __restrict__ out) {
  const int row = blockIdx.x, tid = threadIdx.x;
  const float* x = in + (size_t)row * 768;
  float v0 = x[tid], v1 = x[tid + 256], v2 = x[tid + 512];
  float s = v0 + v1 + v2;
  float s2 = v0 * v0 + v1 * v1 + v2 * v2;
#pragma unroll
  for (int off = 32; off >= 1; off >>= 1) {
    s += __shfl_xor(s, off);
    s2 += __shfl_xor(s2, off);
  }
  __shared__ float red[8];
  const int wv = tid >> 6;
  if ((tid & 63) == 0) { red[wv] = s; red[4 + wv] = s2; }
  __syncthreads();
  s = red[0] + red[1] + red[2] + red[3];
  s2 = red[4] + red[5] + red[6] + red[7];
  float mean = s * (1.f / 768.f);
  float var = s2 * (1.f / 768.f) - mean * mean;
  float rs = rsqrtf(var + 1e-6f);
  float* o = out + (size_t)row * 768;
  o[tid] = (v0 - mean) * rs * sc[tid] + bi[tid];
  o[tid + 256] = (v1 - mean) * rs * sc[tid + 256] + bi[tid + 256];
  o[tid + 512] = (v2 - mean) * rs * sc[tid + 512] + bi[tid + 512];
}

extern "C" void kernel_launch(void* const* d_in, const int* in_sizes, int n_in,
                              void* d_out, int out_size, void* d_ws, size_t ws_size,
                              hipStream_t stream) {
  const float* x   = (const float*)d_in[0];
  const float* Wx0 = (const float*)d_in[1];
  const float* Wh0 = (const float*)d_in[2];
  const float* b0  = (const float*)d_in[3];
  const float* Wx1 = (const float*)d_in[4];
  const float* Wh1 = (const float*)d_in[5];
  const float* b1  = (const float*)d_in[6];
  const float* lns = (const float*)d_in[7];
  const float* lnb = (const float*)d_in[8];
  float* out = (float*)d_out;

  char* p = (char*)d_ws;
  auto alloc = [&](size_t bytes) {
    char* r = p;
    p += (bytes + 255) & ~(size_t)255;
    return r;
  };
  u16* xg   = (u16*)alloc(16384ull * 3072 * 2);
  u16* xbf  = (u16*)alloc(16384ull * 768 * 2);
  u16* Wxp0 = (u16*)alloc(2359296ull * 2);
  u16* Whp0 = (u16*)alloc(2359296ull * 2);
  u16* Wcp  = (u16*)alloc(4718592ull * 2);
  char* sync0 = alloc(393216ull * 2);   // h0buf, h1buf (ring-4 tagged dwords)
  int* h0buf = (int*)sync0;
  int* h1buf = (int*)(sync0 + 393216);

  if ((size_t)(p - (char*)d_ws) > ws_size) {
    fprintf(stderr, "kernel_launch: ws too small: need %zu have %zu\n",
            (size_t)(p - (char*)d_ws), ws_size);
    return;
  }

  hipMemsetAsync(sync0, 0, 393216ull * 2, stream);
  k_cvt<<<12288, 256, 0, stream>>>(x, xbf, 3145728);
  k_pack_wx<<<9216, 256, 0, stream>>>(Wx0, Wxp0);
  k_pack_wh<<<9216, 256, 0, stream>>>(Wh0, Whp0);
  k_pack_wc<<<18432, 256, 0, stream>>>(Wx1, Wh1, Wcp);

  k_gemm<<<3072, 256, 0, stream>>>(xbf, Wxp0, xg);
  k_rec2<<<256, 384, 0, stream>>>(xg, Whp0, Wcp, b0, b1, h0buf, h1buf, (float*)d_out);
  k_ln<<<16384, 256, 0, stream>>>((const float*)d_out, lns, lnb, out);
}

// Round 6
// 2166.858 us; speedup vs baseline: 1.4394x; 1.4394x over previous
//
#include <hip/hip_runtime.h>
#include <stdint.h>
#include <cstdio>

typedef unsigned short u16;
typedef __attribute__((ext_vector_type(8))) __bf16 bf16x8;
typedef __attribute__((ext_vector_type(4))) float f32x4;
typedef __attribute__((ext_vector_type(4))) int i32x4;

#define AGENT __HIP_MEMORY_SCOPE_AGENT

__device__ __forceinline__ float bf2f(u16 u) {
  unsigned int x = ((unsigned int)u) << 16;
  return __builtin_bit_cast(float, x);
}
__device__ __forceinline__ u16 f2bf(float f) {
  unsigned int x = __builtin_bit_cast(unsigned int, f);
  unsigned int r = (x + 0x7fffu + ((x >> 16) & 1u)) >> 16;
  return (u16)r;
}
__device__ __forceinline__ float sigm(float x) { return 1.f / (1.f + __expf(-x)); }
__device__ __forceinline__ float tanh_f(float x) { return 1.f - 2.f / (__expf(2.f * x) + 1.f); }

// ---------- fp32 -> bf16 convert (x) ----------
__global__ __launch_bounds__(256) void k_cvt(const float* __restrict__ in, u16* __restrict__ out, int n4) {
  int i = blockIdx.x * 256 + threadIdx.x;
  if (i >= n4) return;
  float4 f = ((const float4*)in)[i];
  ushort4 o;
  o.x = f2bf(f.x); o.y = f2bf(f.y); o.z = f2bf(f.z); o.w = f2bf(f.w);
  ((ushort4*)out)[i] = o;
}

// ---------- pack Wx [768][3072] -> B-fragment order [nt=192][kt=24][lane=64][j=8] ----------
__global__ __launch_bounds__(256) void k_pack_wx(const float* __restrict__ Wx, u16* __restrict__ Bp) {
  int idx = blockIdx.x * 256 + threadIdx.x;
  if (idx >= 2359296) return;
  int j = idx & 7;
  int l = (idx >> 3) & 63;
  int t = idx >> 9;          // nt*24 + kt
  int kt = t % 24, nt = t / 24;
  int k = kt * 32 + (l >> 4) * 8 + j;
  int n = nt * 16 + (l & 15);
  Bp[idx] = f2bf(Wx[(size_t)k * 3072 + n]);
}

// ---------- pack Wh -> per-member slices [w=32][nt=6][kt=24][lane=64][j=8] ----------
// NEW col order: within a 16-col tile, col cc = 4*vi + q  (vi = unit-in-wave 0..3, q = gate 0..3)
// unit = w*24 + nt*4 + vi ; gcol = q*768 + unit
__global__ __launch_bounds__(256) void k_pack_wh(const float* __restrict__ Wh, u16* __restrict__ Wp) {
  int idx = blockIdx.x * 256 + threadIdx.x;
  if (idx >= 2359296) return;
  int j = idx & 7;
  int l = (idx >> 3) & 63;
  int t = idx >> 9;          // w*144 + nt*24 + kt
  int kt = t % 24;
  int tmp = t / 24;          // w*6 + nt
  int nt = tmp % 6, w = tmp / 6;
  int k = kt * 32 + (l >> 4) * 8 + j;
  int cc = l & 15;
  int vi = cc >> 2, q = cc & 3;
  int gcol = q * 768 + w * 24 + nt * 4 + vi;
  Wp[idx] = f2bf(Wh[(size_t)k * 3072 + gcol]);
}

// ---------- GEMM: C[16384][3072] bf16 = A[16384][768] bf16 @ Bp(packed) ----------
__global__ __launch_bounds__(256, 2) void k_gemm(const u16* __restrict__ A, const u16* __restrict__ Bp,
                                                 u16* __restrict__ C) {
  const int bid = blockIdx.x;
  const int bm = bid & 127, bn = bid >> 7;   // 128 x 24
  const int tid = threadIdx.x, lane = tid & 63, wv = tid >> 6;
  const int wm = wv >> 1, wn = wv & 1;
  const int row0 = bm * 128 + wm * 64;
  const int col0 = bn * 128 + wn * 64;
  const int rlo = lane & 15, rhi = lane >> 4;
  f32x4 acc[4][4] = {};
  const u16* Ab = A + (size_t)(row0 + rlo) * 768 + rhi * 8;
  const u16* Bb = Bp + ((size_t)(bn * 8 + wn * 4) * 24 * 64 + lane) * 8;
#pragma unroll 2
  for (int kt = 0; kt < 24; ++kt) {
    bf16x8 a[4], b[4];
#pragma unroll
    for (int i = 0; i < 4; ++i) a[i] = *(const bf16x8*)(Ab + (size_t)i * 16 * 768 + kt * 32);
#pragma unroll
    for (int j = 0; j < 4; ++j) b[j] = *(const bf16x8*)(Bb + (size_t)j * 24 * 64 * 8 + (size_t)kt * 64 * 8);
#pragma unroll
    for (int i = 0; i < 4; ++i)
#pragma unroll
      for (int j = 0; j < 4; ++j)
        acc[i][j] = __builtin_amdgcn_mfma_f32_16x16x32_bf16(a[i], b[j], acc[i][j], 0, 0, 0);
  }
#pragma unroll
  for (int i = 0; i < 4; ++i)
#pragma unroll
    for (int j = 0; j < 4; ++j)
#pragma unroll
      for (int r = 0; r < 4; ++r) {
        int row = row0 + i * 16 + rhi * 4 + r;
        int col = col0 + j * 16 + rlo;
        C[(size_t)row * 3072 + col] = f2bf(acc[i][j][r]);
      }
}

// ---------- persistent LSTM recurrence ----------
// 256 WGs x 384 threads (6 waves). Logical groups: g = wid&7 (4 seqs), member w = wid>>3 (24 units).
// Wave wv owns units [wv*4, wv*4+4): its 16 MFMA cols = 4 gates x 4 units (col = 4*vi + q).
// Per step: all threads merged-poll+fetch tagged h_{t-1} -> B_A -> stage hlds -> B3 -> MFMA ->
// wave-local 16x4 transpose (no WG barrier) -> cell math in lanes 0-15 -> fire-and-forget publish.
// h published as tagged dwords (bf16_h<<16 | (t+1)), double-buffered by t parity.
__global__ __launch_bounds__(384) void k_rec(
    const u16* __restrict__ xg,    // [16384][3072] bf16, m = seq*512 + t
    const u16* __restrict__ Whp,   // [32][6][24][64][8] packed bf16 (new col order)
    const float* __restrict__ bias,
    int* hbuf,                     // [8 groups][2][3072] tagged dwords (zeroed)
    u16* __restrict__ hout_bf,     // layer 0 out (bf16) or null
    float* __restrict__ hout_f,    // layer 1 out (fp32) or null
    int layer) {
  __shared__ __align__(16) int hlds[4 * 400];   // h_{t-1}[4 seq][768] bf16, rows padded to 400 dw
  __shared__ __align__(16) float wlds[6][68];   // per-wave 16x4 gate transpose scratch

  const int wid = blockIdx.x, g = wid & 7, w = wid >> 3;
  const int tid = threadIdx.x, lane = tid & 63, wv = tid >> 6;

  // ---- Wh fragments -> VGPRs (static indices; stays in registers) ----
  bf16x8 bregE[12], bregO[12];
  {
    const u16* bp = Whp + (((size_t)(w * 6 + wv) * 24) * 64 + lane) * 8;
#pragma unroll
    for (int kk = 0; kk < 12; ++kk) {
      bregE[kk] = *(const bf16x8*)(bp + (size_t)(2 * kk) * 512);
      bregO[kk] = *(const bf16x8*)(bp + (size_t)(2 * kk + 1) * 512);
    }
  }

  // ---- cell role: lanes 0-15 of each wave own cell (seq r, unit vi) ----
  const bool cellt = lane < 16;
  const int vi = lane & 3, r = (lane >> 2) & 3;
  const int unit = w * 24 + wv * 4 + vi;
  const int seq = g * 4 + r;
  float bv0 = 0, bv1 = 0, bv2 = 0, bv3 = 0, xv0 = 0, xv1 = 0, xv2 = 0, xv3 = 0;
  if (cellt) {
    bv0 = bias[unit]; bv1 = bias[768 + unit]; bv2 = bias[1536 + unit]; bv3 = bias[2304 + unit];
    const u16* xr = xg + (size_t)seq * 512 * 3072;
    xv0 = bf2f(xr[unit]); xv1 = bf2f(xr[768 + unit]);
    xv2 = bf2f(xr[1536 + unit]); xv3 = bf2f(xr[2304 + unit]);
  }
  float cst = 0.f;
  const int sl = (lane & 15) < 4 ? (lane & 15) : 3;      // A-frag row (pad rows clamped)
  const int abase = sl * 400 + (lane >> 4) * 4;          // A-frag dword base in hlds
  // poll/stage role: thread tid handles 8 tagged dwords
  const int c = tid;                                     // 0..383
  const int hrow = c / 96, hcol = (c % 96) * 4;          // packed int4 slot in hlds
  int guard = 0;

  __syncthreads();

  for (int t = 0; t < 512; ++t) {
    // ---- merged poll+fetch of h_{t-1}: full tagged load IS the poll (1 RT) ----
    const int expect = t;  // tag written by step t-1 producers (t=0: zeroed buffer)
    int* src = hbuf + (size_t)(g * 2 + (t & 1)) * 3072;
    const int* p0 = src + 8 * c;
    const int* p1 = src + 8 * c + 4;
    i32x4 v0, v1;
    for (;;) {
      asm volatile("global_load_dwordx4 %0, %2, off sc0 sc1\n\t"
                   "global_load_dwordx4 %1, %3, off sc0 sc1\n\t"
                   "s_waitcnt vmcnt(0)"
                   : "=&v"(v0), "=&v"(v1)
                   : "v"(p0), "v"(p1)
                   : "memory");
      bool ok = true;
#pragma unroll
      for (int j = 0; j < 4; ++j)
        ok = ok && ((v0[j] & 0xffff) == expect) && ((v1[j] & 0xffff) == expect);
      if (ok || ++guard > (1 << 22)) break;
    }
    __syncthreads();  // B_A: all waves done reading hlds (MFMA of t-1)

    // stage packed bf16 pairs into hlds
    {
      int4 pk;
      pk.x = (int)(((unsigned)v0[0] >> 16) | ((unsigned)v0[1] & 0xffff0000u));
      pk.y = (int)(((unsigned)v0[2] >> 16) | ((unsigned)v0[3] & 0xffff0000u));
      pk.z = (int)(((unsigned)v1[0] >> 16) | ((unsigned)v1[1] & 0xffff0000u));
      pk.w = (int)(((unsigned)v1[2] >> 16) | ((unsigned)v1[3] & 0xffff0000u));
      *(int4*)&hlds[hrow * 400 + hcol] = pk;
    }
    __syncthreads();  // B3: hlds ready

    // ---- MFMA: gates[4 seq][16 cols of wave tile] = h_{t-1} @ Wh(regs), 2 indep chains ----
    f32x4 a0 = {0, 0, 0, 0}, a1 = {0, 0, 0, 0};
#pragma unroll
    for (int kk = 0; kk < 12; ++kk) {
      bf16x8 afe = *(const bf16x8*)(hlds + abase + (2 * kk) * 16);
      bf16x8 afo = *(const bf16x8*)(hlds + abase + (2 * kk + 1) * 16);
      a0 = __builtin_amdgcn_mfma_f32_16x16x32_bf16(afe, bregE[kk], a0, 0, 0, 0);
      a1 = __builtin_amdgcn_mfma_f32_16x16x32_bf16(afo, bregO[kk], a1, 0, 0, 0);
    }
    a0 += a1;

    // ---- wave-local 16x4 transpose: D[col=lane(0-15)][row r=reg] -> cell lanes ----
    // write: wlds[wv][rr*16 + lane] = a0[rr]; read: lane l2 -> (r2=l2>>2, vi2=l2&3) gets 4 gates
    if (cellt) {
#pragma unroll
      for (int rr = 0; rr < 4; ++rr) wlds[wv][rr * 16 + lane] = a0[rr];
    }
    asm volatile("s_waitcnt lgkmcnt(0)" ::: "memory");
    if (cellt) {
      f32x4 tr = *(const f32x4*)&wlds[wv][r * 16 + vi * 4];  // gates q=0..3 (i,f,g,o)
      float p0g = xv0 + tr[0] + bv0;
      float p1g = xv1 + tr[1] + bv1;
      float p2g = xv2 + tr[2] + bv2;
      float p3g = xv3 + tr[3] + bv3;
      float ig = sigm(p0g), fg = sigm(p1g), gg = tanh_f(p2g), og = sigm(p3g);
      cst = fg * cst + ig * gg;
      float h = og * tanh_f(cst);
      // publish tagged h (fire-and-forget; dword atomicity makes it self-validating)
      int* dst = hbuf + (size_t)(g * 2 + ((t + 1) & 1)) * 3072 + r * 768 + unit;
      int val = (int)(((unsigned)f2bf(h) << 16) | (unsigned)(t + 1));
      __hip_atomic_store(dst, val, __ATOMIC_RELAXED, AGENT);
      // off the critical path: output store + next-step xg prefetch
      size_t o = ((size_t)seq * 512 + t) * 768 + unit;
      if (layer == 0) hout_bf[o] = f2bf(h); else hout_f[o] = h;
      if (t + 1 < 512) {
        const u16* xr = xg + ((size_t)seq * 512 + t + 1) * 3072;
        xv0 = bf2f(xr[unit]); xv1 = bf2f(xr[768 + unit]);
        xv2 = bf2f(xr[1536 + unit]); xv3 = bf2f(xr[2304 + unit]);
      }
    }
  }
}

// ---------- LayerNorm (in-place safe) ----------
__global__ __launch_bounds__(256) void k_ln(const float* __restrict__ in, const float* __restrict__ sc,
                                            const float* __restrict__ bi, float* __restrict__ out) {
  const int row = blockIdx.x, tid = threadIdx.x;
  const float* x = in + (size_t)row * 768;
  float v0 = x[tid], v1 = x[tid + 256], v2 = x[tid + 512];
  float s = v0 + v1 + v2;
  float s2 = v0 * v0 + v1 * v1 + v2 * v2;
#pragma unroll
  for (int off = 32; off >= 1; off >>= 1) {
    s += __shfl_xor(s, off);
    s2 += __shfl_xor(s2, off);
  }
  __shared__ float red[8];
  const int wv = tid >> 6;
  if ((tid & 63) == 0) { red[wv] = s; red[4 + wv] = s2; }
  __syncthreads();
  s = red[0] + red[1] + red[2] + red[3];
  s2 = red[4] + red[5] + red[6] + red[7];
  float mean = s * (1.f / 768.f);
  float var = s2 * (1.f / 768.f) - mean * mean;
  float rs = rsqrtf(var + 1e-6f);
  float* o = out + (size_t)row * 768;
  o[tid] = (v0 - mean) * rs * sc[tid] + bi[tid];
  o[tid + 256] = (v1 - mean) * rs * sc[tid + 256] + bi[tid + 256];
  o[tid + 512] = (v2 - mean) * rs * sc[tid + 512] + bi[tid + 512];
}

extern "C" void kernel_launch(void* const* d_in, const int* in_sizes, int n_in,
                              void* d_out, int out_size, void* d_ws, size_t ws_size,
                              hipStream_t stream) {
  const float* x   = (const float*)d_in[0];
  const float* Wx0 = (const float*)d_in[1];
  const float* Wh0 = (const float*)d_in[2];
  const float* b0  = (const float*)d_in[3];
  const float* Wx1 = (const float*)d_in[4];
  const float* Wh1 = (const float*)d_in[5];
  const float* b1  = (const float*)d_in[6];
  const float* lns = (const float*)d_in[7];
  const float* lnb = (const float*)d_in[8];
  float* out = (float*)d_out;

  char* p = (char*)d_ws;
  auto alloc = [&](size_t bytes) {
    char* r = p;
    p += (bytes + 255) & ~(size_t)255;
    return r;
  };
  u16* xg    = (u16*)alloc(16384ull * 3072 * 2);
  u16* xbf   = (u16*)alloc(16384ull * 768 * 2);
  u16* h0bf  = (u16*)alloc(16384ull * 768 * 2);
  u16* Wxp0  = (u16*)alloc(2359296ull * 2);
  u16* Wxp1  = (u16*)alloc(2359296ull * 2);
  u16* Whp0  = (u16*)alloc(2359296ull * 2);
  u16* Whp1  = (u16*)alloc(2359296ull * 2);
  char* sync0 = alloc(196608ull * 2);   // hbuf0, hbuf1 (tagged dwords)
  int* hbuf0 = (int*)sync0;
  int* hbuf1 = (int*)(sync0 + 196608);

  if ((size_t)(p - (char*)d_ws) > ws_size) {
    fprintf(stderr, "kernel_launch: ws too small: need %zu have %zu\n",
            (size_t)(p - (char*)d_ws), ws_size);
    return;
  }

  hipMemsetAsync(sync0, 0, 196608ull * 2, stream);
  k_cvt<<<12288, 256, 0, stream>>>(x, xbf, 3145728);
  k_pack_wx<<<9216, 256, 0, stream>>>(Wx0, Wxp0);
  k_pack_wx<<<9216, 256, 0, stream>>>(Wx1, Wxp1);
  k_pack_wh<<<9216, 256, 0, stream>>>(Wh0, Whp0);
  k_pack_wh<<<9216, 256, 0, stream>>>(Wh1, Whp1);

  k_gemm<<<3072, 256, 0, stream>>>(xbf, Wxp0, xg);
  k_rec<<<256, 384, 0, stream>>>(xg, Whp0, b0, hbuf0, h0bf, nullptr, 0);
  k_gemm<<<3072, 256, 0, stream>>>(h0bf, Wxp1, xg);
  k_rec<<<256, 384, 0, stream>>>(xg, Whp1, b1, hbuf1, nullptr, (float*)d_out, 1);
  k_ln<<<16384, 256, 0, stream>>>((const float*)d_out, lns, lnb, out);
}